// Round 1
// baseline (2111.089 us; speedup 1.0000x reference)
//
#include <hip/hip_runtime.h>
#include <cmath>

namespace {
constexpr int Bz  = 8;
constexpr int L0c = 384;
constexpr int Lc  = 385;
constexpr int Dc  = 128;
constexpr int Hc  = 8;
constexpr int KHc = 16;           // 2 distance groups * 8 heads
constexpr int NITER = 4;
constexpr int BLDc = Bz * Lc * Dc;   // 394240
constexpr float NEGV = 1e9f;

// workspace layout (float offsets)
constexpr size_t OFF_UNARY = 0;
constexpr size_t OFF_QZ    = OFF_UNARY + BLDc;
constexpr size_t OFF_QZS   = OFF_QZ + BLDc;
constexpr size_t OFF_MPAD  = OFF_QZS + BLDc;                 // B*L = 3080 (pad 3584)
constexpr size_t OFF_TAB   = OFF_MPAD + 3584;
constexpr size_t OFF_TBA   = OFF_TAB + (size_t)2 * Hc * Dc * Dc;
constexpr size_t OFF_QI    = OFF_TBA + (size_t)2 * Hc * Dc * Dc;
constexpr size_t SZQ       = (size_t)Bz * KHc * Lc * Dc;     // 6307840
constexpr size_t OFF_QJ    = OFF_QI + SZQ;
constexpr size_t OFF_QH    = OFF_QJ + SZQ;
constexpr size_t OFF_GP    = OFF_QH + (size_t)Bz * Hc * Lc * Lc;
constexpr size_t OFF_HP    = OFF_GP + (size_t)Hc * BLDc;
} // namespace

// ---------------------------------------------------------------- init
__global__ __launch_bounds__(256) void k_init(
    const float* __restrict__ x, const float* __restrict__ mask,
    float* __restrict__ unary, float* __restrict__ qz, float* __restrict__ mpad) {
  int idx = blockIdx.x * 256 + threadIdx.x;
  if (idx >= BLDc) return;
  int d  = idx & (Dc - 1);
  int zi = idx >> 7;
  int i  = zi % Lc;
  int z  = zi / Lc;
  float u = 0.f, m = 1.f;
  if (i > 0) {
    u = x[((size_t)z * L0c + (i - 1)) * Dc + d];
    m = (mask[(size_t)z * L0c + (i - 1)] != 0.f) ? 1.f : 0.f;
  }
  unary[idx] = u;
  qz[idx]    = u * m;
  if (d == 0) mpad[zi] = m;
}

// T[k,a,b,c] (c innermost) -> Tab[kc][a][b], Tba[kc][b][a]
__global__ __launch_bounds__(256) void k_packT(
    const float* __restrict__ T, float* __restrict__ Tab, float* __restrict__ Tba) {
  int idx = blockIdx.x * 256 + threadIdx.x;
  if (idx >= 2 * Dc * Dc * Hc) return;
  int c = idx & 7;
  int t = idx >> 3;
  int b = t & 127; t >>= 7;
  int a = t & 127; t >>= 7;
  int k = t;
  float v = T[idx];
  int kc = k * Hc + c;
  Tab[((size_t)kc * Dc + a) * Dc + b] = v;
  Tba[((size_t)kc * Dc + b) * Dc + a] = v;
}

// ---------------------------------------------------------------- softmax over d (per (z,i) row)
__global__ __launch_bounds__(128) void k_softmax_z(
    const float* __restrict__ qz, const float* __restrict__ mpad, float* __restrict__ qzs) {
  int row = blockIdx.x;     // z*L + i
  int t = threadIdx.x;
  float v = qz[(size_t)row * Dc + t];
  float m = v;
  #pragma unroll
  for (int o = 32; o > 0; o >>= 1) m = fmaxf(m, __shfl_xor(m, o));
  __shared__ float red[2];
  if ((t & 63) == 0) red[t >> 6] = m;
  __syncthreads();
  m = fmaxf(red[0], red[1]);
  __syncthreads();
  float e = __expf(v - m);
  float s = e;
  #pragma unroll
  for (int o = 32; o > 0; o >>= 1) s += __shfl_xor(s, o);
  if ((t & 63) == 0) red[t >> 6] = s;
  __syncthreads();
  s = red[0] + red[1];
  qzs[(size_t)row * Dc + t] = e / s * mpad[row];
}

// ---------------------------------------------------------------- Qi/Qj: qzs @ Tab, qzs @ Tba
// Qi[z][kc][i][b] = sum_a qzs[z,i,a]*T[k,a,b,c];  Qj[z][kc][j][a] = sum_b qzs[z,j,b]*T[k,a,b,c]
__global__ __launch_bounds__(256) void k_qiqj(
    const float* __restrict__ qzs, const float* __restrict__ Tab,
    const float* __restrict__ Tba, float* __restrict__ Qi, float* __restrict__ Qj) {
  __shared__ float At[64][33];
  __shared__ float B1[32][128];
  __shared__ float B2[32][128];
  const int it = blockIdx.x, z = blockIdx.y, kc = blockIdx.z;
  const int i0 = it * 64;
  const int tid = threadIdx.x;
  const int tx = tid & 15, ty = tid >> 4;
  float a1[4][8] = {};
  float a2[4][8] = {};
  const float* Az = qzs + (size_t)z * Lc * Dc;
  const float* T1 = Tab + (size_t)kc * Dc * Dc;
  const float* T2 = Tba + (size_t)kc * Dc * Dc;
  for (int k0 = 0; k0 < Dc; k0 += 32) {
    __syncthreads();
    for (int e = tid; e < 64 * 32; e += 256) {
      int r = e >> 5, cc = e & 31;
      int i = i0 + r;
      At[r][cc] = (i < Lc) ? Az[(size_t)i * Dc + k0 + cc] : 0.f;
    }
    for (int e = tid; e < 32 * 128; e += 256) {
      int r = e >> 7, cc = e & 127;
      B1[r][cc] = T1[(size_t)(k0 + r) * Dc + cc];
      B2[r][cc] = T2[(size_t)(k0 + r) * Dc + cc];
    }
    __syncthreads();
    #pragma unroll 4
    for (int kk = 0; kk < 32; kk++) {
      float av[4], b1v[8], b2v[8];
      #pragma unroll
      for (int r = 0; r < 4; r++) av[r] = At[ty * 4 + r][kk];
      #pragma unroll
      for (int q = 0; q < 8; q++) { b1v[q] = B1[kk][tx * 8 + q]; b2v[q] = B2[kk][tx * 8 + q]; }
      #pragma unroll
      for (int r = 0; r < 4; r++)
        #pragma unroll
        for (int q = 0; q < 8; q++) {
          a1[r][q] = fmaf(av[r], b1v[q], a1[r][q]);
          a2[r][q] = fmaf(av[r], b2v[q], a2[r][q]);
        }
    }
  }
  const size_t base = (size_t)(z * KHc + kc) * Lc * Dc;
  for (int r = 0; r < 4; r++) {
    int i = i0 + ty * 4 + r;
    if (i >= Lc) break;
    float4* p1 = reinterpret_cast<float4*>(Qi + base + (size_t)i * Dc + tx * 8);
    float4* p2 = reinterpret_cast<float4*>(Qj + base + (size_t)i * Dc + tx * 8);
    p1[0] = make_float4(a1[r][0], a1[r][1], a1[r][2], a1[r][3]);
    p1[1] = make_float4(a1[r][4], a1[r][5], a1[r][6], a1[r][7]);
    p2[0] = make_float4(a2[r][0], a2[r][1], a2[r][2], a2[r][3]);
    p2[1] = make_float4(a2[r][4], a2[r][5], a2[r][6], a2[r][7]);
  }
}

// ---------------------------------------------------------------- F -> qh logits
// qh[z,c,i,j] = 128 * sum_d Qi[z,k(i,j),c,i,d]*qzs[z,j,d]; diag/invalid -> -1e9
__global__ __launch_bounds__(256) void k_F(
    const float* __restrict__ Qi, const float* __restrict__ qzs,
    const float* __restrict__ mpad, float* __restrict__ qh) {
  __shared__ float A0[64][33];
  __shared__ float A1[64][33];
  __shared__ float Bt[64][33];
  const int ti = blockIdx.x / 7, tj = blockIdx.x % 7;
  const int z = blockIdx.y, c = blockIdx.z;
  const int i0 = ti * 64, j0 = tj * 64;
  const bool mixed = (ti == tj);
  const int tid = threadIdx.x;
  const int tx = tid & 15, ty = tid >> 4;
  float acc0[4][4] = {};
  float acc1[4][4] = {};
  const float* Qb0 = Qi + (size_t)(z * KHc + c) * Lc * Dc;        // k=0
  const float* Qb1 = Qi + (size_t)(z * KHc + Hc + c) * Lc * Dc;   // k=1
  const float* Bz_ = qzs + (size_t)z * Lc * Dc;
  const float* Qsel = (!mixed && tj < ti) ? Qb1 : Qb0;
  for (int k0 = 0; k0 < Dc; k0 += 32) {
    __syncthreads();
    for (int e = tid; e < 64 * 32; e += 256) {
      int r = e >> 5, cc = e & 31;
      int i = i0 + r, j = j0 + r;
      A0[r][cc] = (i < Lc) ? Qsel[(size_t)i * Dc + k0 + cc] : 0.f;
      if (mixed) A1[r][cc] = (i < Lc) ? Qb1[(size_t)i * Dc + k0 + cc] : 0.f;
      Bt[r][cc] = (j < Lc) ? Bz_[(size_t)j * Dc + k0 + cc] : 0.f;
    }
    __syncthreads();
    #pragma unroll 4
    for (int kk = 0; kk < 32; kk++) {
      float a0v[4], bv[4];
      #pragma unroll
      for (int r = 0; r < 4; r++) a0v[r] = A0[ty * 4 + r][kk];
      #pragma unroll
      for (int q = 0; q < 4; q++) bv[q] = Bt[tx * 4 + q][kk];
      if (mixed) {
        float a1v[4];
        #pragma unroll
        for (int r = 0; r < 4; r++) a1v[r] = A1[ty * 4 + r][kk];
        #pragma unroll
        for (int r = 0; r < 4; r++)
          #pragma unroll
          for (int q = 0; q < 4; q++) acc1[r][q] = fmaf(a1v[r], bv[q], acc1[r][q]);
      }
      #pragma unroll
      for (int r = 0; r < 4; r++)
        #pragma unroll
        for (int q = 0; q < 4; q++) acc0[r][q] = fmaf(a0v[r], bv[q], acc0[r][q]);
    }
  }
  float* qrow = qh + (size_t)(z * Hc + c) * Lc * Lc;
  #pragma unroll
  for (int r = 0; r < 4; r++) {
    int i = i0 + ty * 4 + r;
    if (i >= Lc) break;
    float mi = mpad[z * Lc + i];
    #pragma unroll
    for (int q = 0; q < 4; q++) {
      int j = j0 + tx * 4 + q;
      if (j >= Lc) continue;
      float mj = mpad[z * Lc + j];
      float val;
      if (i == j || mi == 0.f || mj == 0.f) {
        val = -NEGV;
      } else {
        float s = (mixed && i > j) ? acc1[r][q] : acc0[r][q];
        val = s * 128.f;
      }
      qrow[(size_t)i * Lc + j] = val;
    }
  }
}

// ---------------------------------------------------------------- softmax over j; zero root row i=0
__global__ __launch_bounds__(128) void k_softmax_h(float* __restrict__ qh) {
  const int row = blockIdx.x;      // (z*H + c)*L + i
  const int i = row % Lc;
  const int t = threadIdx.x;
  float* p = qh + (size_t)row * Lc;
  if (i == 0) {
    for (int j = t; j < Lc; j += 128) p[j] = 0.f;
    return;
  }
  float v[4];
  float m = -INFINITY;
  #pragma unroll
  for (int q = 0; q < 4; q++) {
    int j = t + q * 128;
    v[q] = (j < Lc) ? p[j] : -INFINITY;
    m = fmaxf(m, v[q]);
  }
  #pragma unroll
  for (int o = 32; o > 0; o >>= 1) m = fmaxf(m, __shfl_xor(m, o));
  __shared__ float red[2];
  if ((t & 63) == 0) red[t >> 6] = m;
  __syncthreads();
  m = fmaxf(red[0], red[1]);
  __syncthreads();
  float s = 0.f;
  #pragma unroll
  for (int q = 0; q < 4; q++) {
    int j = t + q * 128;
    v[q] = (j < Lc) ? __expf(v[q] - m) : 0.f;
    s += v[q];
  }
  #pragma unroll
  for (int o = 32; o > 0; o >>= 1) s += __shfl_xor(s, o);
  if ((t & 63) == 0) red[t >> 6] = s;
  __syncthreads();
  s = red[0] + red[1];
  float inv = 1.f / s;
  #pragma unroll
  for (int q = 0; q < 4; q++) {
    int j = t + q * 128;
    if (j < Lc) p[j] = v[q] * inv;
  }
}

// ---------------------------------------------------------------- G partials
// Gp[c][z][i][a] = sum_j qh[z,c,i,j] * Qj[z,k(i,j),c,j,a]
__global__ __launch_bounds__(256) void k_G(
    const float* __restrict__ qh, const float* __restrict__ Qj, float* __restrict__ Gp) {
  __shared__ float Qt[64][33];    // [i][j-chunk]
  __shared__ float Bt[32][128];   // Qj chunk [j][a]
  const int it = blockIdx.x, z = blockIdx.y, c = blockIdx.z;
  const int i0 = it * 64;
  const int tid = threadIdx.x, tx = tid & 15, ty = tid >> 4;
  float acc[4][8] = {};
  const float* qb = qh + (size_t)(z * Hc + c) * Lc * Lc;
  for (int jc = 0; jc < Lc; jc += 32) {
    __syncthreads();
    for (int e = tid; e < 64 * 32; e += 256) {
      int r = e >> 5, cc = e & 31;
      int i = i0 + r, j = jc + cc;
      Qt[r][cc] = (i < Lc && j < Lc) ? qb[(size_t)i * Lc + j] : 0.f;
    }
    int jmax = min(jc + 31, Lc - 1);
    int imax = min(i0 + 63, Lc - 1);
    bool hasUp  = (i0 < jmax);    // exists i<j in this tile-chunk
    bool hasLow = (imax > jc);    // exists i>j
    bool needMask = hasUp && hasLow;
    for (int p = 0; p < 2; p++) {
      if (p == 0 && !hasUp) continue;
      if (p == 1 && !hasLow) continue;
      __syncthreads();
      const float* Qjb = Qj + (size_t)(z * KHc + p * Hc + c) * Lc * Dc;
      for (int e = tid; e < 32 * 128; e += 256) {
        int r = e >> 7, cc = e & 127;
        int j = jc + r;
        Bt[r][cc] = (j < Lc) ? Qjb[(size_t)j * Dc + cc] : 0.f;
      }
      __syncthreads();
      #pragma unroll 4
      for (int kk = 0; kk < 32; kk++) {
        int j = jc + kk;
        float bv[8];
        #pragma unroll
        for (int q = 0; q < 8; q++) bv[q] = Bt[kk][tx * 8 + q];
        #pragma unroll
        for (int r = 0; r < 4; r++) {
          float a = Qt[ty * 4 + r][kk];
          if (needMask) {
            int i = i0 + ty * 4 + r;
            bool keep = (p == 0) ? (i < j) : (i > j);
            a = keep ? a : 0.f;
          }
          #pragma unroll
          for (int q = 0; q < 8; q++) acc[r][q] = fmaf(a, bv[q], acc[r][q]);
        }
      }
    }
  }
  float* gp = Gp + ((size_t)c * Bz + z) * Lc * Dc;
  for (int r = 0; r < 4; r++) {
    int i = i0 + ty * 4 + r;
    if (i >= Lc) break;
    float4* pp = reinterpret_cast<float4*>(gp + (size_t)i * Dc + tx * 8);
    pp[0] = make_float4(acc[r][0], acc[r][1], acc[r][2], acc[r][3]);
    pp[1] = make_float4(acc[r][4], acc[r][5], acc[r][6], acc[r][7]);
  }
}

// ---------------------------------------------------------------- Hm partials
// Hp[c][z][j][b] = sum_i qh[z,c,i,j] * Qi[z,k(i,j),c,i,b]
__global__ __launch_bounds__(256) void k_Hm(
    const float* __restrict__ qh, const float* __restrict__ Qi, float* __restrict__ Hp) {
  __shared__ float Qt[64][33];    // transposed: [j][i-chunk]
  __shared__ float Bt[32][128];   // Qi chunk [i][b]
  const int jt = blockIdx.x, z = blockIdx.y, c = blockIdx.z;
  const int j0 = jt * 64;
  const int tid = threadIdx.x, tx = tid & 15, ty = tid >> 4;
  float acc[4][8] = {};
  const float* qb = qh + (size_t)(z * Hc + c) * Lc * Lc;
  for (int ic = 0; ic < Lc; ic += 32) {
    __syncthreads();
    for (int e = tid; e < 64 * 32; e += 256) {
      int r = e >> 6, cc = e & 63;     // r: i-offset (0..31), cc: j-offset (0..63)
      int i = ic + r, j = j0 + cc;
      Qt[cc][r] = (i < Lc && j < Lc) ? qb[(size_t)i * Lc + j] : 0.f;
    }
    int imax = min(ic + 31, Lc - 1);
    int jmax = min(j0 + 63, Lc - 1);
    bool hasUp  = (ic < jmax);    // exists i<j
    bool hasLow = (imax > j0);    // exists i>j
    bool needMask = hasUp && hasLow;
    for (int p = 0; p < 2; p++) {
      if (p == 0 && !hasUp) continue;
      if (p == 1 && !hasLow) continue;
      __syncthreads();
      const float* Qib = Qi + (size_t)(z * KHc + p * Hc + c) * Lc * Dc;
      for (int e = tid; e < 32 * 128; e += 256) {
        int r = e >> 7, cc = e & 127;
        int i = ic + r;
        Bt[r][cc] = (i < Lc) ? Qib[(size_t)i * Dc + cc] : 0.f;
      }
      __syncthreads();
      #pragma unroll 4
      for (int kk = 0; kk < 32; kk++) {
        int i = ic + kk;
        float bv[8];
        #pragma unroll
        for (int q = 0; q < 8; q++) bv[q] = Bt[kk][tx * 8 + q];
        #pragma unroll
        for (int r = 0; r < 4; r++) {
          float a = Qt[ty * 4 + r][kk];
          if (needMask) {
            int j = j0 + ty * 4 + r;
            bool keep = (p == 0) ? (i < j) : (i > j);
            a = keep ? a : 0.f;
          }
          #pragma unroll
          for (int q = 0; q < 8; q++) acc[r][q] = fmaf(a, bv[q], acc[r][q]);
        }
      }
    }
  }
  float* hp = Hp + ((size_t)c * Bz + z) * Lc * Dc;
  for (int r = 0; r < 4; r++) {
    int j = j0 + ty * 4 + r;
    if (j >= Lc) break;
    float4* pp = reinterpret_cast<float4*>(hp + (size_t)j * Dc + tx * 8);
    pp[0] = make_float4(acc[r][0], acc[r][1], acc[r][2], acc[r][3]);
    pp[1] = make_float4(acc[r][4], acc[r][5], acc[r][6], acc[r][7]);
  }
}

// ---------------------------------------------------------------- combine: qz = (unary + G + Hm)*m1
__global__ __launch_bounds__(256) void k_combine(
    const float* __restrict__ unary, const float* __restrict__ Gp,
    const float* __restrict__ Hp, const float* __restrict__ mpad,
    float* __restrict__ qz, float* __restrict__ out, int last) {
  int idx = blockIdx.x * 256 + threadIdx.x;
  if (idx >= BLDc) return;
  int d  = idx & (Dc - 1);
  int zi = idx >> 7;
  int i  = zi % Lc;
  int z  = zi / Lc;
  float s = unary[idx];
  #pragma unroll
  for (int c = 0; c < Hc; c++) s += Gp[(size_t)c * BLDc + idx] + Hp[(size_t)c * BLDc + idx];
  s *= mpad[zi];
  if (last) {
    if (i > 0) out[((size_t)z * L0c + (i - 1)) * Dc + d] = s;
  } else {
    qz[idx] = s;
  }
}

// ---------------------------------------------------------------- launch
extern "C" void kernel_launch(void* const* d_in, const int* in_sizes, int n_in,
                              void* d_out, int out_size, void* d_ws, size_t ws_size,
                              hipStream_t stream) {
  const float* x    = (const float*)d_in[0];
  const float* mask = (const float*)d_in[1];
  const float* tern = (const float*)d_in[2];
  float* ws = (float*)d_ws;

  float* unary = ws + OFF_UNARY;
  float* qz    = ws + OFF_QZ;
  float* qzs   = ws + OFF_QZS;
  float* mpad  = ws + OFF_MPAD;
  float* tab   = ws + OFF_TAB;
  float* tba   = ws + OFF_TBA;
  float* qi    = ws + OFF_QI;
  float* qj    = ws + OFF_QJ;
  float* qh    = ws + OFF_QH;
  float* gp    = ws + OFF_GP;
  float* hp    = ws + OFF_HP;

  k_init<<<(BLDc + 255) / 256, 256, 0, stream>>>(x, mask, unary, qz, mpad);
  k_packT<<<(2 * Dc * Dc * Hc) / 256, 256, 0, stream>>>(tern, tab, tba);

  for (int it = 0; it < NITER; it++) {
    k_softmax_z<<<Bz * Lc, 128, 0, stream>>>(qz, mpad, qzs);
    k_qiqj<<<dim3(7, Bz, KHc), 256, 0, stream>>>(qzs, tab, tba, qi, qj);
    k_F<<<dim3(49, Bz, Hc), 256, 0, stream>>>(qi, qzs, mpad, qh);
    k_softmax_h<<<Bz * Hc * Lc, 128, 0, stream>>>(qh);
    k_G<<<dim3(7, Bz, Hc), 256, 0, stream>>>(qh, qj, gp);
    k_Hm<<<dim3(7, Bz, Hc), 256, 0, stream>>>(qh, qi, hp);
    k_combine<<<(BLDc + 255) / 256, 256, 0, stream>>>(
        unary, gp, hp, mpad, qz, (float*)d_out, (it == NITER - 1) ? 1 : 0);
  }
}